// Round 3
// baseline (869.973 us; speedup 1.0000x reference)
//
#include <hip/hip_runtime.h>
#include <math.h>

typedef __attribute__((ext_vector_type(8))) short short8;
typedef __attribute__((ext_vector_type(4))) float f32x4;

#define GLOBAL_AS __attribute__((address_space(1)))
#define LDS_AS __attribute__((address_space(3)))

__device__ __forceinline__ unsigned short f2bf(float f) {
  union { float f; unsigned u; } v; v.f = f;
  unsigned r = v.u + 0x7fffu + ((v.u >> 16) & 1u);
  return (unsigned short)(r >> 16);
}

// fp32 -> bf16 (RNE), 4 elements/thread
__global__ void cvt_f32_to_bf16(const float* __restrict__ in,
                                unsigned short* __restrict__ out, int n4) {
  int i = blockIdx.x * blockDim.x + threadIdx.x;
  if (i < n4) {
    const float4 v = ((const float4*)in)[i];
    ushort4 o;
    o.x = f2bf(v.x); o.y = f2bf(v.y); o.z = f2bf(v.z); o.w = f2bf(v.w);
    ((ushort4*)out)[i] = o;
  }
}

// C = A @ B^T. A:[M][K], B:[N][K] bf16 row-major. 256x256 tile, BK=64,
// 8 waves (2Mx4N), 4-phase/K-tile schedule (= m201's 8-phase per 2 K-tiles),
// K-half [256][32] slots in a 4-slot LDS ring per operand, counted vmcnt(4).
// Swizzle sigma(byte) = byte ^ (((byte>>7)&7)<<4): involution, 16B-granular,
// flips bits 6:4 by row bits 3:1 -> 16 lanes/row-group spread over 8 bank-quads
// (2-way aliasing = free, m136). Applied as: linear global_load_lds dest +
// inverse-sigma'd global source + sigma'd ds_read addr (rule #21).
// EPI==0: out bf16( gelu_exact((acc+bias[n])*scale[n]) ); EPI==1: fp32, no gelu.
template <int EPI>
__global__ __launch_bounds__(512, 2) void gemm256_8ph(
    const unsigned short* __restrict__ A, const unsigned short* __restrict__ B,
    const float* __restrict__ bias, const float* __restrict__ scale,
    void* __restrict__ Cout, int M, int N, int K) {
  constexpr int BM = 256, BN = 256;
  __shared__ __attribute__((aligned(16))) unsigned short ldsA[4][8192];
  __shared__ __attribute__((aligned(16))) unsigned short ldsB[4][8192];

  const int NT = K >> 6;                 // K-tiles of 64
  const int nTn = N / BN;
  const int bid = blockIdx.x;
  const int cpx = gridDim.x >> 3;        // grid % 8 == 0 for our shapes
  const int wg = (bid & 7) * cpx + (bid >> 3);   // bijective XCD swizzle
  const int tm = wg / nTn, tn = wg % nTn;

  const int tid = threadIdx.x;
  const int w = tid >> 6, l = tid & 63;
  const int wr = w >> 2, wc = w & 3;     // wave 2x4 -> per-wave 128x64 out
  const int lr = l & 15, g = l >> 4;

  const unsigned short* Ag = A + (size_t)tm * BM * K;
  const unsigned short* Bg = B + (size_t)tn * BN * K;

  // staging: slot = [256][32] bf16 = 16 KiB = 1024 x 16B segs; thread covers
  // segs {tid, tid+512}; LDS dest linear (wave base + lane*16 by HW); global
  // source pre-inverse-swizzled so sigma'd ds_reads see logical row-major data.
  size_t gs[2];
#pragma unroll
  for (int sgi = 0; sgi < 2; ++sgi) {
    int p = tid * 16 + sgi * 8192;
    int sp = p ^ (((p >> 7) & 7) << 4);          // sigma (involution)
    gs[sgi] = (size_t)(sp >> 6) * K + ((sp & 63) >> 1);
  }
  const int ldsWaveOff = w * 512;        // shorts; wave-uniform base

  auto STAGE = [&](int tau, int ks, const unsigned short* gb,
                   unsigned short (*slotArr)[8192]) {
    if (tau >= NT) return;               // wave-uniform guard (tail no-op)
    unsigned short* sl = slotArr[(2 * tau + ks) & 3];
    const size_t ko = ((size_t)tau << 6) + (ks << 5);
    __builtin_amdgcn_global_load_lds((const GLOBAL_AS void*)(gb + gs[0] + ko),
                                     (LDS_AS void*)(sl + ldsWaveOff), 16, 0, 0);
    __builtin_amdgcn_global_load_lds((const GLOBAL_AS void*)(gb + gs[1] + ko),
                                     (LDS_AS void*)(sl + 4096 + ldsWaveOff), 16, 0, 0);
  };

  auto LD = [&](const unsigned short* slot, int row) -> short8 {
    int by = row * 64 + g * 16;
    by ^= ((by >> 7) & 7) << 4;          // sigma
    return *(const short8*)((const char*)slot + by);
  };

  f32x4 acc[8][4] = {};

  // prologue: stream elements 0..5, then guarantee tile 0 resident
  STAGE(0, 0, Ag, ldsA); STAGE(0, 0, Bg, ldsB);
  STAGE(0, 1, Ag, ldsA); STAGE(0, 1, Bg, ldsB);
  STAGE(1, 0, Ag, ldsA); STAGE(1, 0, Bg, ldsB);
  asm volatile("s_waitcnt vmcnt(4)" ::: "memory");
  __builtin_amdgcn_s_barrier();

  for (int kt = 0; kt < NT; ++kt) {
    const unsigned short* As0 = ldsA[(2 * kt) & 3];
    const unsigned short* Bs0 = ldsB[(2 * kt) & 3];
    const unsigned short* As1 = ldsA[(2 * kt + 1) & 3];
    const unsigned short* Bs1 = ldsB[(2 * kt + 1) & 3];
    const int ar = wr * 128 + lr;
    const int br = wc * 64 + lr;
    short8 a[4], b[4];

    // ---- phase 0: ks0, m-lo (8 ds_read)
#pragma unroll
    for (int m = 0; m < 4; ++m) a[m] = LD(As0, ar + m * 16);
#pragma unroll
    for (int n = 0; n < 4; ++n) b[n] = LD(Bs0, br + n * 16);
    STAGE(kt + 1, 1, Ag, ldsA);   // overwrites (kt-1,1)A: last read iter kt-1 ph3
    __builtin_amdgcn_s_barrier();
    __builtin_amdgcn_s_setprio(1);
#pragma unroll
    for (int m = 0; m < 4; ++m)
#pragma unroll
      for (int n = 0; n < 4; ++n)
        acc[m][n] = __builtin_amdgcn_mfma_f32_16x16x32_bf16(a[m], b[n], acc[m][n], 0, 0, 0);
    __builtin_amdgcn_s_setprio(0);
    __builtin_amdgcn_s_barrier();

    // ---- phase 1: ks0, m-hi (4 ds_read)
#pragma unroll
    for (int m = 0; m < 4; ++m) a[m] = LD(As0, ar + 64 + m * 16);
    STAGE(kt + 1, 1, Bg, ldsB);   // overwrites (kt-1,1)B: last read iter kt-1 ph3
    __builtin_amdgcn_s_barrier();
    __builtin_amdgcn_s_setprio(1);
#pragma unroll
    for (int m = 0; m < 4; ++m)
#pragma unroll
      for (int n = 0; n < 4; ++n)
        acc[4 + m][n] = __builtin_amdgcn_mfma_f32_16x16x32_bf16(a[m], b[n], acc[4 + m][n], 0, 0, 0);
    __builtin_amdgcn_s_setprio(0);
    __builtin_amdgcn_s_barrier();

    // ---- phase 2: ks1, m-lo (8 ds_read)
#pragma unroll
    for (int m = 0; m < 4; ++m) a[m] = LD(As1, ar + m * 16);
#pragma unroll
    for (int n = 0; n < 4; ++n) b[n] = LD(Bs1, br + n * 16);
    STAGE(kt + 2, 0, Ag, ldsA);   // overwrites (kt,0)A: last read phase 1 (safe)
    __builtin_amdgcn_s_barrier();
    __builtin_amdgcn_s_setprio(1);
#pragma unroll
    for (int m = 0; m < 4; ++m)
#pragma unroll
      for (int n = 0; n < 4; ++n)
        acc[m][n] = __builtin_amdgcn_mfma_f32_16x16x32_bf16(a[m], b[n], acc[m][n], 0, 0, 0);
    __builtin_amdgcn_s_setprio(0);
    __builtin_amdgcn_s_barrier();

    // ---- phase 3: ks1, m-hi (4 ds_read)
#pragma unroll
    for (int m = 0; m < 4; ++m) a[m] = LD(As1, ar + 64 + m * 16);
    STAGE(kt + 2, 0, Bg, ldsB);   // overwrites (kt,0)B: last read phase 0 (safe)
    __builtin_amdgcn_s_barrier();
    __builtin_amdgcn_s_setprio(1);
#pragma unroll
    for (int m = 0; m < 4; ++m)
#pragma unroll
      for (int n = 0; n < 4; ++n)
        acc[4 + m][n] = __builtin_amdgcn_mfma_f32_16x16x32_bf16(a[m], b[n], acc[4 + m][n], 0, 0, 0);
    __builtin_amdgcn_s_setprio(0);
    // counted vmcnt once per K-tile: leaves (kt+2,0)A+B in flight;
    // ledger => tile kt+1 fully resident at next-iter entry.
    if (kt + 2 < NT) { asm volatile("s_waitcnt vmcnt(4)" ::: "memory"); }
    else             { asm volatile("s_waitcnt vmcnt(0)" ::: "memory"); }
    __builtin_amdgcn_s_barrier();
  }

  // epilogue — C/D layout: col = lane&15, row = (lane>>4)*4 + j  [m89/m91]
  const int orow = tm * BM + wr * 128;
  const int ocol = tn * BN + wc * 64;
  const int rsub = g * 4;
#pragma unroll
  for (int n = 0; n < 4; ++n) {
    const int gn = ocol + n * 16 + lr;
    const float bv = bias[gn];
    const float sv = scale[gn];
#pragma unroll
    for (int m = 0; m < 8; ++m) {
#pragma unroll
      for (int j = 0; j < 4; ++j) {
        const int gm = orow + m * 16 + rsub + j;
        float v = (acc[m][n][j] + bv) * sv;
        if (EPI == 0) {
          const float gl = 0.5f * v * (1.0f + erff(v * 0.70710678118654752440f));
          ((unsigned short*)Cout)[(size_t)gm * N + gn] = f2bf(gl);
        } else {
          ((float*)Cout)[(size_t)gm * N + gn] = v;
        }
      }
    }
  }
}

extern "C" void kernel_launch(void* const* d_in, const int* in_sizes, int n_in,
                              void* d_out, int out_size, void* d_ws, size_t ws_size,
                              hipStream_t stream) {
  const int T = 16384, H = 2048, H2 = 4096;
  const float* x  = (const float*)d_in[0];
  const float* w1 = (const float*)d_in[1];
  const float* b1 = (const float*)d_in[2];
  const float* s1 = (const float*)d_in[3];
  const float* w2 = (const float*)d_in[4];
  const float* b2 = (const float*)d_in[5];
  const float* s2 = (const float*)d_in[6];

  // workspace (bf16): xb 64MiB | w1b 16MiB | w2b 16MiB | h 128MiB  (224 MiB)
  unsigned short* xb  = (unsigned short*)d_ws;
  unsigned short* w1b = xb  + (size_t)T  * H;
  unsigned short* w2b = w1b + (size_t)H2 * H;
  unsigned short* hb  = w2b + (size_t)H  * H2;

  int n4 = T * H / 4;
  cvt_f32_to_bf16<<<(n4 + 255) / 256, 256, 0, stream>>>(x, xb, n4);
  n4 = H2 * H / 4;
  cvt_f32_to_bf16<<<(n4 + 255) / 256, 256, 0, stream>>>(w1, w1b, n4);
  cvt_f32_to_bf16<<<(n4 + 255) / 256, 256, 0, stream>>>(w2, w2b, n4);

  // fc1 + bias + scale + exact GELU -> h (bf16): M=T, N=2H, K=H, grid 1024
  gemm256_8ph<0><<<(T / 256) * (H2 / 256), 512, 0, stream>>>(
      xb, w1b, b1, s1, (void*)hb, T, H2, H);
  // fc2 + bias + scale -> y (fp32): M=T, N=H, K=2H, grid 512
  gemm256_8ph<1><<<(T / 256) * (H / 256), 512, 0, stream>>>(
      hb, w2b, b2, s2, d_out, T, H, H2);
}

// Round 4
// 851.939 us; speedup vs baseline: 1.0212x; 1.0212x over previous
//
#include <hip/hip_runtime.h>
#include <math.h>

typedef __attribute__((ext_vector_type(8))) short short8;
typedef __attribute__((ext_vector_type(4))) float f32x4;

#define GLOBAL_AS __attribute__((address_space(1)))
#define LDS_AS __attribute__((address_space(3)))

__device__ __forceinline__ unsigned short f2bf(float f) {
  union { float f; unsigned u; } v; v.f = f;
  unsigned r = v.u + 0x7fffu + ((v.u >> 16) & 1u);
  return (unsigned short)(r >> 16);
}

// fp32 -> bf16 (RNE), 4 elements/thread
__global__ void cvt_f32_to_bf16(const float* __restrict__ in,
                                unsigned short* __restrict__ out, int n4) {
  int i = blockIdx.x * blockDim.x + threadIdx.x;
  if (i < n4) {
    const float4 v = ((const float4*)in)[i];
    ushort4 o;
    o.x = f2bf(v.x); o.y = f2bf(v.y); o.z = f2bf(v.z); o.w = f2bf(v.w);
    ((ushort4*)out)[i] = o;
  }
}

// C = A @ B^T. A:[M][K], B:[N][K] bf16 row-major. 256x256 tile, BK=64,
// 8 waves (2Mx4N), 4 phases/K-tile, K-half [256][32] slots in a 4-slot ring
// per operand (period 2 in tile idx -> kt-loop unrolled x2 so every slot
// index / ds_read offset is a compile-time immediate).
// Swizzle sigma(x)=x^(((x>>7)&7)<<4): additive over m*1024/half*4096 (mask
// depends only on lr bits 3:1) -> ONE precomputed swizzled base VGPR per
// operand, all reads at base+imm. Linear gload-LDS dest + inverse-sigma
// global source + sigma'd read (rule #21). Bank conflicts measured 0.
// Publication discipline: vmcnt wait BEFORE a phase-closing barrier
// publishes staged slots to ALL waves (per-wave vmcnt + barrier):
//   Wb @ ph1-end publishes (t,1) for ph2; Wa @ ph3-end publishes (t+1,0).
// Steady-state counts vmcnt(4); tails derived by ledger (see per-site comments).
// EPI==0: out bf16( gelu_exact((acc+bias[n])*scale[n]) ); EPI==1: fp32, no gelu.
template <int EPI>
__global__ __launch_bounds__(512, 2) void gemm256_8ph(
    const unsigned short* __restrict__ A, const unsigned short* __restrict__ B,
    const float* __restrict__ bias, const float* __restrict__ scale,
    void* __restrict__ Cout, int M, int N, int K) {
  constexpr int BM = 256, BN = 256;
  __shared__ __attribute__((aligned(16))) unsigned short ldsA[32768]; // 4 x 16KiB slots
  __shared__ __attribute__((aligned(16))) unsigned short ldsB[32768];

  const int NT = K >> 6;                 // K-tiles of 64 (even: 32 or 64)
  const int nTn = N / BN;
  const int bid = blockIdx.x;
  const int cpx = gridDim.x >> 3;        // grid % 8 == 0 for our shapes
  const int wg = (bid & 7) * cpx + (bid >> 3);   // bijective XCD swizzle
  const int tm = wg / nTn, tn = wg % nTn;

  const int tid = threadIdx.x;
  const int w = tid >> 6, l = tid & 63;
  const int wr = w >> 2, wc = w & 3;     // wave 2x4 -> per-wave 128x64 out
  const int lr = l & 15, g = l >> 4;

  const unsigned short* Ag = A + (size_t)tm * BM * K;
  const unsigned short* Bg = B + (size_t)tn * BN * K;

  // ---- staging addresses (inverse-sigma'd global source), computed once ----
  size_t gs0, gs1;
  {
    int p0 = tid * 16, p1 = tid * 16 + 8192;
    int sp0 = p0 ^ (((p0 >> 7) & 7) << 4);
    int sp1 = p1 ^ (((p1 >> 7) & 7) << 4);
    gs0 = (size_t)(sp0 >> 6) * K + ((sp0 & 63) >> 1);
    gs1 = (size_t)(sp1 >> 6) * K + ((sp1 & 63) >> 1);
  }
  const unsigned short* pA0 = Ag + gs0; const unsigned short* pA1 = Ag + gs1;
  const unsigned short* pB0 = Bg + gs0; const unsigned short* pB1 = Bg + gs1;
  const int ldsWaveOff = w * 512;        // shorts; wave-uniform base

#define STAGE_A(tau, ks, SLOT)                                                   \
  if ((tau) < NT) {                                                              \
    const size_t ko_ = ((size_t)(tau) << 6) + ((ks) << 5);                       \
    __builtin_amdgcn_global_load_lds((const GLOBAL_AS void*)(pA0 + ko_),         \
        (LDS_AS void*)(ldsA + (SLOT)*8192 + ldsWaveOff), 16, 0, 0);              \
    __builtin_amdgcn_global_load_lds((const GLOBAL_AS void*)(pA1 + ko_),         \
        (LDS_AS void*)(ldsA + (SLOT)*8192 + 4096 + ldsWaveOff), 16, 0, 0);       \
  }
#define STAGE_B(tau, ks, SLOT)                                                   \
  if ((tau) < NT) {                                                              \
    const size_t ko_ = ((size_t)(tau) << 6) + ((ks) << 5);                       \
    __builtin_amdgcn_global_load_lds((const GLOBAL_AS void*)(pB0 + ko_),         \
        (LDS_AS void*)(ldsB + (SLOT)*8192 + ldsWaveOff), 16, 0, 0);              \
    __builtin_amdgcn_global_load_lds((const GLOBAL_AS void*)(pB1 + ko_),         \
        (LDS_AS void*)(ldsB + (SLOT)*8192 + 4096 + ldsWaveOff), 16, 0, 0);       \
  }

  // ---- precomputed swizzled LDS read bases (all loop VALU eliminated) ----
  // sigma is additive over +m*1024 (bits 10-11), +half*4096 (bit 12),
  // +slot*16384 (bits 14-15): mask bits 6:4 come from byte bits 9:7 = lr bits
  // 3:1 only -> one base per operand, everything else an immediate.
  int ab = ((wr * 128 + lr) << 6) + (g << 4);
  int aoff = ab ^ (((ab >> 7) & 7) << 4);
  int bb = ((wc * 64 + lr) << 6) + (g << 4);
  int boff = bb ^ (((bb >> 7) & 7) << 4);
  const char* ldsAb = (const char*)ldsA + aoff;
  const char* ldsBb = (const char*)ldsB + boff;
#define LDA8(S, H, m) (*(const short8*)(ldsAb + (S)*16384 + (H)*4096 + (m)*1024))
#define LDB8(S, n)    (*(const short8*)(ldsBb + (S)*16384 + (n)*1024))

  f32x4 acc[8][4] = {};
  short8 a[4], b[4];

#define OPEN_MFMA(ROW0)                                                          \
  __builtin_amdgcn_s_barrier();                                                  \
  asm volatile("s_waitcnt lgkmcnt(0)" ::: "memory");                             \
  __builtin_amdgcn_s_setprio(1);                                                 \
  _Pragma("unroll") for (int m = 0; m < 4; ++m)                                  \
  _Pragma("unroll") for (int n = 0; n < 4; ++n)                                  \
    acc[(ROW0) + m][n] = __builtin_amdgcn_mfma_f32_16x16x32_bf16(                \
        a[m], b[n], acc[(ROW0) + m][n], 0, 0, 0);                                \
  __builtin_amdgcn_s_setprio(0);

  // prologue: (0,0)->slots 0 | (0,1)->1 | (1,0)->2 ; publish (0,0)
  STAGE_A(0, 0, 0) STAGE_B(0, 0, 0)
  STAGE_A(0, 1, 1) STAGE_B(0, 1, 1)
  STAGE_A(1, 0, 2) STAGE_B(1, 0, 2)
  asm volatile("s_waitcnt vmcnt(4)" ::: "memory");
  __builtin_amdgcn_s_barrier();

  for (int kt = 0; kt < NT; kt += 2) {
    const bool full = (kt + 2 < NT);
    // ================= tile kt (slots 0=ks0, 1=ks1) =================
    // ph0
#pragma unroll
    for (int m = 0; m < 4; ++m) a[m] = LDA8(0, 0, m);
#pragma unroll
    for (int n = 0; n < 4; ++n) b[n] = LDB8(0, n);
    STAGE_A(kt + 1, 1, 3)           // slot3 last read: prev pair body-2 ph2/3
    OPEN_MFMA(0)
    __builtin_amdgcn_s_barrier();
    // ph1
#pragma unroll
    for (int m = 0; m < 4; ++m) a[m] = LDA8(0, 1, m);
    STAGE_B(kt + 1, 1, 3)
    OPEN_MFMA(4)
    // Wb(t=kt): publish (kt,1); queue {(kt,1)AB,(kt+1,0)AB,(kt+1,1)AB} -> 4
    asm volatile("s_waitcnt vmcnt(4)" ::: "memory");
    __builtin_amdgcn_s_barrier();
    // ph2
#pragma unroll
    for (int m = 0; m < 4; ++m) a[m] = LDA8(1, 0, m);
#pragma unroll
    for (int n = 0; n < 4; ++n) b[n] = LDB8(1, n);
    STAGE_A(kt + 2, 0, 0)           // slot0 last read: ph1 (barrier-closed)
    OPEN_MFMA(0)
    __builtin_amdgcn_s_barrier();
    // ph3
#pragma unroll
    for (int m = 0; m < 4; ++m) a[m] = LDA8(1, 1, m);
    STAGE_B(kt + 2, 0, 0)
    OPEN_MFMA(4)
    // Wa(t=kt): publish (kt+1,0); full queue 6 -> 4 | tail queue 4 -> 2
    if (full) { asm volatile("s_waitcnt vmcnt(4)" ::: "memory"); }
    else      { asm volatile("s_waitcnt vmcnt(2)" ::: "memory"); }
    __builtin_amdgcn_s_barrier();
    // ================= tile kt+1 (slots 2=ks0, 3=ks1) ===============
    // ph0
#pragma unroll
    for (int m = 0; m < 4; ++m) a[m] = LDA8(2, 0, m);
#pragma unroll
    for (int n = 0; n < 4; ++n) b[n] = LDB8(2, n);
    STAGE_A(kt + 2, 1, 1)           // slot1 last read: body-1 ph2/3
    OPEN_MFMA(0)
    __builtin_amdgcn_s_barrier();
    // ph1
#pragma unroll
    for (int m = 0; m < 4; ++m) a[m] = LDA8(2, 1, m);
    STAGE_B(kt + 2, 1, 1)
    OPEN_MFMA(4)
    // Wb(t=kt+1): publish (kt+1,1); full 4 | tail: only (kt+1,1) left -> 0
    if (full) { asm volatile("s_waitcnt vmcnt(4)" ::: "memory"); }
    else      { asm volatile("s_waitcnt vmcnt(0)" ::: "memory"); }
    __builtin_amdgcn_s_barrier();
    // ph2
#pragma unroll
    for (int m = 0; m < 4; ++m) a[m] = LDA8(3, 0, m);
#pragma unroll
    for (int n = 0; n < 4; ++n) b[n] = LDB8(3, n);
    STAGE_A(kt + 3, 0, 2)           // slot2 last read: ph0/ph1 above
    OPEN_MFMA(0)
    __builtin_amdgcn_s_barrier();
    // ph3
#pragma unroll
    for (int m = 0; m < 4; ++m) a[m] = LDA8(3, 1, m);
    STAGE_B(kt + 3, 0, 2)
    OPEN_MFMA(4)
    // Wa(t=kt+1): publish (kt+2,0); full 4 | tail nothing -> 0
    if (full) { asm volatile("s_waitcnt vmcnt(4)" ::: "memory"); }
    else      { asm volatile("s_waitcnt vmcnt(0)" ::: "memory"); }
    __builtin_amdgcn_s_barrier();
  }

  // epilogue — C/D layout: col = lane&15, row = (lane>>4)*4 + j  [m89/m91]
  const int orow = tm * BM + wr * 128;
  const int ocol = tn * BN + wc * 64;
  const int rsub = g * 4;
#pragma unroll
  for (int n = 0; n < 4; ++n) {
    const int gn = ocol + n * 16 + lr;
    const float bv = bias[gn];
    const float sv = scale[gn];
#pragma unroll
    for (int m = 0; m < 8; ++m) {
#pragma unroll
      for (int j = 0; j < 4; ++j) {
        const int gm = orow + m * 16 + rsub + j;
        float v = (acc[m][n][j] + bv) * sv;
        if (EPI == 0) {
          const float gl = 0.5f * v * (1.0f + erff(v * 0.70710678118654752440f));
          ((unsigned short*)Cout)[(size_t)gm * N + gn] = f2bf(gl);
        } else {
          ((float*)Cout)[(size_t)gm * N + gn] = v;
        }
      }
    }
  }
#undef STAGE_A
#undef STAGE_B
#undef LDA8
#undef LDB8
#undef OPEN_MFMA
}

extern "C" void kernel_launch(void* const* d_in, const int* in_sizes, int n_in,
                              void* d_out, int out_size, void* d_ws, size_t ws_size,
                              hipStream_t stream) {
  const int T = 16384, H = 2048, H2 = 4096;
  const float* x  = (const float*)d_in[0];
  const float* w1 = (const float*)d_in[1];
  const float* b1 = (const float*)d_in[2];
  const float* s1 = (const float*)d_in[3];
  const float* w2 = (const float*)d_in[4];
  const float* b2 = (const float*)d_in[5];
  const float* s2 = (const float*)d_in[6];

  // workspace (bf16): xb 64MiB | w1b 16MiB | w2b 16MiB | h 128MiB  (224 MiB)
  unsigned short* xb  = (unsigned short*)d_ws;
  unsigned short* w1b = xb  + (size_t)T  * H;
  unsigned short* w2b = w1b + (size_t)H2 * H;
  unsigned short* hb  = w2b + (size_t)H  * H2;

  int n4 = T * H / 4;
  cvt_f32_to_bf16<<<(n4 + 255) / 256, 256, 0, stream>>>(x, xb, n4);
  n4 = H2 * H / 4;
  cvt_f32_to_bf16<<<(n4 + 255) / 256, 256, 0, stream>>>(w1, w1b, n4);
  cvt_f32_to_bf16<<<(n4 + 255) / 256, 256, 0, stream>>>(w2, w2b, n4);

  // fc1 + bias + scale + exact GELU -> h (bf16): M=T, N=2H, K=H, grid 1024
  gemm256_8ph<0><<<(T / 256) * (H2 / 256), 512, 0, stream>>>(
      xb, w1b, b1, s1, (void*)hb, T, H2, H);
  // fc2 + bias + scale -> y (fp32): M=T, N=H, K=2H, grid 512
  gemm256_8ph<1><<<(T / 256) * (H / 256), 512, 0, stream>>>(
      hb, w2b, b2, s2, d_out, T, H, H2);
}

// Round 6
// 812.688 us; speedup vs baseline: 1.0705x; 1.0483x over previous
//
#include <hip/hip_runtime.h>
#include <math.h>

typedef __attribute__((ext_vector_type(8))) short short8;
typedef __attribute__((ext_vector_type(4))) float f32x4;

#define GLOBAL_AS __attribute__((address_space(1)))
#define LDS_AS __attribute__((address_space(3)))

__device__ __forceinline__ unsigned short f2bf(float f) {
  union { float f; unsigned u; } v; v.f = f;
  unsigned r = v.u + 0x7fffu + ((v.u >> 16) & 1u);
  return (unsigned short)(r >> 16);
}

// fp32 -> bf16 (RNE), 4 elements/thread
__global__ void cvt_f32_to_bf16(const float* __restrict__ in,
                                unsigned short* __restrict__ out, int n4) {
  int i = blockIdx.x * blockDim.x + threadIdx.x;
  if (i < n4) {
    const float4 v = ((const float4*)in)[i];
    ushort4 o;
    o.x = f2bf(v.x); o.y = f2bf(v.y); o.z = f2bf(v.z); o.w = f2bf(v.w);
    ((ushort4*)out)[i] = o;
  }
}

// C = A @ B^T. A:[M][K], B:[N][K] bf16 row-major. 256x256 tile, BK=64, 8 waves.
// v5: FULL-LINE STAGING. Half-tiles are [128 rows][64 k] bf16 (128-B rows) so
// each global_load_lds wave-op covers 8 full 128B lines (was: 16 half-lines
// with [256][32] K-half slots -> transaction-rate-limited at 9.3 B/cyc/CU).
// LDS (128 KiB): A = [2 dbuf][2 M-half][16 KiB] at bytes [0,64K);
//                B = [4-slot ring of N-half][16 KiB] at [64K,128K), slot=(2t+h)&3.
// Stage stream per tile t: ph0: Alo,Ahi(t+1)->dbuf^1 + Bhi(t+1)->slot(2t+3)&3
//   (all freed after t-1 ph3, protected by its closing barrier);
//   ph3: Blo(t+2)->slot(2t)&3 (= Blo(t), last ds_read at ph2, protected by
//   ph2's closing barrier). ONE counted vmcnt(2) per tile at ph3 (leaves
//   Blo(t+2) in flight; publishes all of tile t+1 incl. prior Blo(t+1)).
// Tail: vmcnt(0) when t+2>=NT. Prologue: A0,Blo0,Bhi0,Blo1 then vmcnt(2).
// Swizzle sigma'(byte) = byte ^ ((row&7)<<4) (G4 D=128 fix): row bits 2:0 =
// byte bits 9:7 flip 16B-chunk bits 6:4; involution, intra-row; additive over
// m*2048 / slot strides; ks*64 folded into per-lane ks0/ks1 bases.
// Quarter-wave (16-lane) servicing: chunk = g ^ (lr&7) -> 8 chunks x 2 lanes
// = 2-way aliasing = free (m136). Staging writes lane-linear = conflict-free.
// EPI==0: out bf16(gelu_exact((acc+bias[n])*scale[n])); EPI==1: fp32, no gelu.
template <int EPI>
__global__ __launch_bounds__(512, 2) void gemm256_v5(
    const unsigned short* __restrict__ A, const unsigned short* __restrict__ B,
    const float* __restrict__ bias, const float* __restrict__ scale,
    void* __restrict__ Cout, int M, int N, int K) {
  constexpr int BM = 256, BN = 256;
  __shared__ __attribute__((aligned(16))) unsigned short ldsAll[65536]; // 128 KiB

  const int NT = K >> 6;                 // K-tiles of 64 (even: 32 or 64)
  const int nTn = N / BN;
  const int bid = blockIdx.x;
  const int cpx = gridDim.x >> 3;        // grid % 8 == 0 for our shapes
  const int wg = (bid & 7) * cpx + (bid >> 3);   // bijective XCD swizzle
  const int tm = wg / nTn, tn = wg % nTn;

  const int tid = threadIdx.x;
  const int w = tid >> 6, l = tid & 63;
  const int wr = w >> 2, wc = w & 3;     // wave 2x4 -> per-wave 128x64 out
  const int lr = l & 15, g = l >> 4;

  const unsigned short* Ag = A + (size_t)tm * BM * K;
  const unsigned short* Bg = B + (size_t)tn * BN * K;

  // ---- staging source (inverse-sigma'd global, FULL 128B rows per 8 lanes) --
  // thread covers 16B seg at byte p = tid*16 (+ seg*8192) of a half-tile:
  // row = p>>7 = tid>>3 (+64), intra-row byte = (tid&7)*16 ^ ((row&7)<<4).
  const int rowt = tid >> 3;                       // 0..63
  const int colsh = ((((tid & 7) * 16) ^ ((rowt & 7) << 4)) >> 1); // shorts
  const size_t segK = (size_t)64 * K;              // seg1: +64 rows
  const unsigned short* pA0g = Ag + (size_t)rowt * K + colsh;            // A half 0
  const unsigned short* pA1g = Ag + ((size_t)128 + rowt) * K + colsh;    // A half 1
  const unsigned short* pB0g = Bg + (size_t)rowt * K + colsh;            // B half 0
  const unsigned short* pB1g = Bg + ((size_t)128 + rowt) * K + colsh;    // B half 1

  char* const LB = (char*)ldsAll;
  const int wl = w * 1024;               // wave-uniform LDS byte off (+lane*16 HW)

#define STAGE_AH(tau, h, DB)                                                     \
  if ((tau) < NT) {                                                              \
    const unsigned short* q_ = ((h) ? pA1g : pA0g) + (size_t)(tau) * 64;         \
    __builtin_amdgcn_global_load_lds((const GLOBAL_AS void*)q_,                  \
        (LDS_AS void*)(LB + (DB) * 32768 + (h) * 16384 + wl), 16, 0, 0);         \
    __builtin_amdgcn_global_load_lds((const GLOBAL_AS void*)(q_ + segK),         \
        (LDS_AS void*)(LB + (DB) * 32768 + (h) * 16384 + 8192 + wl), 16, 0, 0);  \
  }
#define STAGE_BH(tau, h, SLOT)                                                   \
  if ((tau) < NT) {                                                              \
    const unsigned short* q_ = ((h) ? pB1g : pB0g) + (size_t)(tau) * 64;         \
    __builtin_amdgcn_global_load_lds((const GLOBAL_AS void*)q_,                  \
        (LDS_AS void*)(LB + 65536 + (SLOT) * 16384 + wl), 16, 0, 0);             \
    __builtin_amdgcn_global_load_lds((const GLOBAL_AS void*)(q_ + segK),         \
        (LDS_AS void*)(LB + 65536 + (SLOT) * 16384 + 8192 + wl), 16, 0, 0);      \
  }

  // ---- sigma'd ds_read bases: everything else compile-time immediates ----
  const int sig0 = (g * 16) ^ ((lr & 7) << 4);         // ks=0 chunk
  const int sig1 = (64 + g * 16) ^ ((lr & 7) << 4);    // ks=1 chunk
  const char* Ab0 = LB + wr * 16384 + lr * 128 + sig0;  // + DB*32768 + m*2048
  const char* Ab1 = LB + wr * 16384 + lr * 128 + sig1;
  const char* Bb0 = LB + 65536 + (wc >> 1) * 16384 + (wc & 1) * 8192 + lr * 128 + sig0;
  const char* Bb1 = LB + 65536 + (wc >> 1) * 16384 + (wc & 1) * 8192 + lr * 128 + sig1;
#define LDA8(KS, DB, m) (*(const short8*)(((KS) ? Ab1 : Ab0) + (DB) * 32768 + (m) * 2048))
#define LDB8(KS, TP, n) (*(const short8*)(((KS) ? Bb1 : Bb0) + (TP) * 32768 + (n) * 2048))

  f32x4 acc[8][4] = {};
  short8 a[4], b[4];

#define OPEN_MFMA(ROW0)                                                          \
  __builtin_amdgcn_s_barrier();                                                  \
  asm volatile("s_waitcnt lgkmcnt(0)" ::: "memory");                             \
  __builtin_amdgcn_s_setprio(1);                                                 \
  _Pragma("unroll") for (int m = 0; m < 4; ++m)                                  \
  _Pragma("unroll") for (int n = 0; n < 4; ++n)                                  \
    acc[(ROW0) + m][n] = __builtin_amdgcn_mfma_f32_16x16x32_bf16(                \
        a[m], b[n], acc[(ROW0) + m][n], 0, 0, 0);                                \
  __builtin_amdgcn_s_setprio(0);

// One K-tile: 4 phases. DB/TP: buffer parity (=t&1). SBHI: slot for Bhi(t+1);
// SBLO: slot for Blo(t+2). FULL: t+2<NT (counted wait) else drain.
#define TILE_BODY(T_, DB_, TP_, SBHI_, SBLO_, FULL_)                             \
  { /* ph0: ks0, m0-3 (8 ds_read) + stage A(t+1), Bhi(t+1) */                    \
    _Pragma("unroll") for (int m = 0; m < 4; ++m) a[m] = LDA8(0, DB_, m);        \
    _Pragma("unroll") for (int n = 0; n < 4; ++n) b[n] = LDB8(0, TP_, n);        \
    STAGE_AH((T_) + 1, 0, (DB_) ^ 1)                                             \
    STAGE_AH((T_) + 1, 1, (DB_) ^ 1)                                             \
    STAGE_BH((T_) + 1, 1, SBHI_)                                                 \
    OPEN_MFMA(0)                                                                 \
    __builtin_amdgcn_s_barrier();                                                \
    /* ph1: ks0, m4-7 (4 ds_read, reuse b) */                                    \
    _Pragma("unroll") for (int m = 0; m < 4; ++m) a[m] = LDA8(0, DB_, 4 + m);    \
    OPEN_MFMA(4)                                                                 \
    __builtin_amdgcn_s_barrier();                                                \
    /* ph2: ks1, m0-3 (8 ds_read) */                                             \
    _Pragma("unroll") for (int m = 0; m < 4; ++m) a[m] = LDA8(1, DB_, m);        \
    _Pragma("unroll") for (int n = 0; n < 4; ++n) b[n] = LDB8(1, TP_, n);        \
    OPEN_MFMA(0)                                                                 \
    __builtin_amdgcn_s_barrier();                                                \
    /* ph3: ks1, m4-7 + stage Blo(t+2) (slot freed by ph2's closing barrier) */  \
    _Pragma("unroll") for (int m = 0; m < 4; ++m) a[m] = LDA8(1, DB_, 4 + m);    \
    STAGE_BH((T_) + 2, 0, SBLO_)                                                 \
    OPEN_MFMA(4)                                                                 \
    if (FULL_) { asm volatile("s_waitcnt vmcnt(2)" ::: "memory"); }              \
    else       { asm volatile("s_waitcnt vmcnt(0)" ::: "memory"); }              \
    __builtin_amdgcn_s_barrier();                                                \
  }

  // prologue: A(0)->dbuf0, Blo(0)->slot0, Bhi(0)->slot1, Blo(1)->slot2;
  // publish tile 0 (first 8 loads), leave Blo(1) in flight -> vmcnt(2).
  STAGE_AH(0, 0, 0)
  STAGE_AH(0, 1, 0)
  STAGE_BH(0, 0, 0)
  STAGE_BH(0, 1, 1)
  STAGE_BH(1, 0, 2)
  asm volatile("s_waitcnt vmcnt(2)" ::: "memory");
  __builtin_amdgcn_s_barrier();

  for (int kt = 0; kt < NT; kt += 2) {
    // tile kt (even): dbuf 0, B slots {0,1}; Bhi(kt+1)->3, Blo(kt+2)->0
    TILE_BODY(kt, 0, 0, 3, 0, (kt + 2 < NT))
    // tile kt+1 (odd): dbuf 1, B slots {2,3}; Bhi(kt+2)->1, Blo(kt+3)->2
    TILE_BODY(kt + 1, 1, 1, 1, 2, (kt + 3 < NT))
  }

  // epilogue — C/D layout: col = lane&15, row = (lane>>4)*4 + j  [m89/m91]
  const int orow = tm * BM + wr * 128;
  const int ocol = tn * BN + wc * 64;
  const int rsub = g * 4;
#pragma unroll
  for (int n = 0; n < 4; ++n) {
    const int gn = ocol + n * 16 + lr;
    const float bv = bias[gn];
    const float sv = scale[gn];
#pragma unroll
    for (int m = 0; m < 8; ++m) {
#pragma unroll
      for (int j = 0; j < 4; ++j) {
        const int gm = orow + m * 16 + rsub + j;
        float v = (acc[m][n][j] + bv) * sv;
        if (EPI == 0) {
          const float gl = 0.5f * v * (1.0f + erff(v * 0.70710678118654752440f));
          ((unsigned short*)Cout)[(size_t)gm * N + gn] = f2bf(gl);
        } else {
          ((float*)Cout)[(size_t)gm * N + gn] = v;
        }
      }
    }
  }
#undef STAGE_AH
#undef STAGE_BH
#undef LDA8
#undef LDB8
#undef OPEN_MFMA
#undef TILE_BODY
}

extern "C" void kernel_launch(void* const* d_in, const int* in_sizes, int n_in,
                              void* d_out, int out_size, void* d_ws, size_t ws_size,
                              hipStream_t stream) {
  const int T = 16384, H = 2048, H2 = 4096;
  const float* x  = (const float*)d_in[0];
  const float* w1 = (const float*)d_in[1];
  const float* b1 = (const float*)d_in[2];
  const float* s1 = (const float*)d_in[3];
  const float* w2 = (const float*)d_in[4];
  const float* b2 = (const float*)d_in[5];
  const float* s2 = (const float*)d_in[6];

  // workspace (bf16): xb 64MiB | w1b 16MiB | w2b 16MiB | h 128MiB  (224 MiB)
  unsigned short* xb  = (unsigned short*)d_ws;
  unsigned short* w1b = xb  + (size_t)T  * H;
  unsigned short* w2b = w1b + (size_t)H2 * H;
  unsigned short* hb  = w2b + (size_t)H  * H2;

  int n4 = T * H / 4;
  cvt_f32_to_bf16<<<(n4 + 255) / 256, 256, 0, stream>>>(x, xb, n4);
  n4 = H2 * H / 4;
  cvt_f32_to_bf16<<<(n4 + 255) / 256, 256, 0, stream>>>(w1, w1b, n4);
  cvt_f32_to_bf16<<<(n4 + 255) / 256, 256, 0, stream>>>(w2, w2b, n4);

  // fc1 + bias + scale + exact GELU -> h (bf16): M=T, N=2H, K=H, grid 1024
  gemm256_v5<0><<<(T / 256) * (H2 / 256), 512, 0, stream>>>(
      xb, w1b, b1, s1, (void*)hb, T, H2, H);
  // fc2 + bias + scale -> y (fp32): M=T, N=H, K=2H, grid 512
  gemm256_v5<1><<<(T / 256) * (H / 256), 512, 0, stream>>>(
      hb, w2b, b2, s2, d_out, T, H, H2);
}

// Round 7
// 792.566 us; speedup vs baseline: 1.0977x; 1.0254x over previous
//
#include <hip/hip_runtime.h>
#include <math.h>

typedef __attribute__((ext_vector_type(8))) short short8;
typedef __attribute__((ext_vector_type(4))) float f32x4;

#define GLOBAL_AS __attribute__((address_space(1)))
#define LDS_AS __attribute__((address_space(3)))

__device__ __forceinline__ unsigned short f2bf(float f) {
  union { float f; unsigned u; } v; v.f = f;
  unsigned r = v.u + 0x7fffu + ((v.u >> 16) & 1u);
  return (unsigned short)(r >> 16);
}

// fp32 -> bf16 (RNE), 4 elements/thread
__global__ void cvt_f32_to_bf16(const float* __restrict__ in,
                                unsigned short* __restrict__ out, int n4) {
  int i = blockIdx.x * blockDim.x + threadIdx.x;
  if (i < n4) {
    const float4 v = ((const float4*)in)[i];
    ushort4 o;
    o.x = f2bf(v.x); o.y = f2bf(v.y); o.z = f2bf(v.z); o.w = f2bf(v.w);
    ((ushort4*)out)[i] = o;
  }
}

// C = A @ B^T. A:[M][K], B:[N][K] bf16 row-major. 256x256 tile, BK=64, 8 waves.
// v6: EVEN STAGE SPREAD (m201 cadence) — exactly ONE half-tile (2 x
// global_load_lds) issued per phase, instead of v5's 6-in-ph0 burst:
//   ph0: A-lo(t+1)->dbuf^1   (old A-lo(t-1): last read ph3(t-1), barrier-closed)
//   ph1: A-hi(t+1)->dbuf^1   (old A-hi(t-1): last read ph3(t-1))
//   ph2: B-hi(t+1)->slot(2t+3)&3 (old B-hi(t-1): last reg-load ph2(t-1))
//   ph3: B-lo(t+2)->slot(2t)&3   (old B-lo(t): last reg-load ph2(t))
// ONE counted vmcnt(2) per tile at ph3 (before the closing barrier):
//   queue = [Blo(t+1)2, Alo(t+1)2, Ahi(t+1)2, Bhi(t+1)2, Blo(t+2)2] (10)
//   -> completes 8 oldest = publishes ALL of tile t+1; leaves Blo(t+2).
//   Every load gets >=3 phases (~4800 cyc) of slack before its covering wait.
// Tail: vmcnt(0) when t+2>=NT (stages guarded off, wave-uniform). NT even.
// Raw asm s_barrier (not builtin) so no compiler-attached vmcnt drain (H1).
// LDS (128 KiB): A [2 dbuf][2 M-half][16 KiB] @ [0,64K);
//                B [4-slot N-half ring][16 KiB] @ [64K,128K), slot=(2t+h)&3.
// Swizzle sigma'(byte)=byte^((row&7)<<4), row=byte>>7 in a half-tile: involution,
// intra-row, additive over m*2048/half/slot strides. Reads: 16-lane groups hit
// 8 chunks x 2 lanes = 2-way = free (measured 0 conflicts). Staging: linear
// LDS dest + inverse-sigma global source (rule #21).
// EPI==0: out bf16(gelu_exact((acc+bias[n])*scale[n])); EPI==1: fp32, no gelu.
template <int EPI>
__global__ __launch_bounds__(512, 2) void gemm256_v6(
    const unsigned short* __restrict__ A, const unsigned short* __restrict__ B,
    const float* __restrict__ bias, const float* __restrict__ scale,
    void* __restrict__ Cout, int M, int N, int K) {
  constexpr int BM = 256, BN = 256;
  __shared__ __attribute__((aligned(16))) unsigned short ldsAll[65536]; // 128 KiB

  const int NT = K >> 6;                 // K-tiles of 64 (even)
  const int nTn = N / BN;
  const int bid = blockIdx.x;
  const int cpx = gridDim.x >> 3;        // grid % 8 == 0 for our shapes
  const int wg = (bid & 7) * cpx + (bid >> 3);   // bijective XCD swizzle
  const int tm = wg / nTn, tn = wg % nTn;

  const int tid = threadIdx.x;
  const int w = tid >> 6, l = tid & 63;
  const int wr = w >> 2, wc = w & 3;     // wave 2x4 -> per-wave 128x64 out
  const int lr = l & 15, g = l >> 4;

  const unsigned short* Ag = A + (size_t)tm * BM * K;
  const unsigned short* Bg = B + (size_t)tn * BN * K;

  // ---- staging source (inverse-sigma'd global, full 128B rows) ----
  const int rowt = tid >> 3;                       // 0..63
  const int colsh = ((((tid & 7) * 16) ^ ((rowt & 7) << 4)) >> 1); // shorts
  const size_t segK = (size_t)64 * K;              // seg1: +64 rows
  const unsigned short* pA0g = Ag + (size_t)rowt * K + colsh;
  const unsigned short* pA1g = Ag + ((size_t)128 + rowt) * K + colsh;
  const unsigned short* pB0g = Bg + (size_t)rowt * K + colsh;
  const unsigned short* pB1g = Bg + ((size_t)128 + rowt) * K + colsh;

  char* const LB = (char*)ldsAll;
  const int wl = w * 1024;               // wave-uniform LDS byte off (+lane*16 HW)

#define BARRIER() asm volatile("s_barrier" ::: "memory")

#define STAGE_AH(tau, h, DB)                                                     \
  if ((tau) < NT) {                                                              \
    const unsigned short* q_ = ((h) ? pA1g : pA0g) + (size_t)(tau) * 64;         \
    __builtin_amdgcn_global_load_lds((const GLOBAL_AS void*)q_,                  \
        (LDS_AS void*)(LB + (DB) * 32768 + (h) * 16384 + wl), 16, 0, 0);         \
    __builtin_amdgcn_global_load_lds((const GLOBAL_AS void*)(q_ + segK),         \
        (LDS_AS void*)(LB + (DB) * 32768 + (h) * 16384 + 8192 + wl), 16, 0, 0);  \
  }
#define STAGE_BH(tau, h, SLOT)                                                   \
  if ((tau) < NT) {                                                              \
    const unsigned short* q_ = ((h) ? pB1g : pB0g) + (size_t)(tau) * 64;         \
    __builtin_amdgcn_global_load_lds((const GLOBAL_AS void*)q_,                  \
        (LDS_AS void*)(LB + 65536 + (SLOT) * 16384 + wl), 16, 0, 0);             \
    __builtin_amdgcn_global_load_lds((const GLOBAL_AS void*)(q_ + segK),         \
        (LDS_AS void*)(LB + 65536 + (SLOT) * 16384 + 8192 + wl), 16, 0, 0);      \
  }

  // ---- sigma'd ds_read bases: all offsets compile-time immediates ----
  const int sig0 = (g * 16) ^ ((lr & 7) << 4);         // ks=0 chunk
  const int sig1 = (64 + g * 16) ^ ((lr & 7) << 4);    // ks=1 chunk
  const char* Ab0 = LB + wr * 16384 + lr * 128 + sig0;  // + DB*32768 + m*2048
  const char* Ab1 = LB + wr * 16384 + lr * 128 + sig1;
  const char* Bb0 = LB + 65536 + (wc >> 1) * 16384 + (wc & 1) * 8192 + lr * 128 + sig0;
  const char* Bb1 = LB + 65536 + (wc >> 1) * 16384 + (wc & 1) * 8192 + lr * 128 + sig1;
#define LDA8(KS, DB, m) (*(const short8*)(((KS) ? Ab1 : Ab0) + (DB) * 32768 + (m) * 2048))
#define LDB8(KS, TP, n) (*(const short8*)(((KS) ? Bb1 : Bb0) + (TP) * 32768 + (n) * 2048))

  f32x4 acc[8][4] = {};
  short8 a[4], b[4];

#define OPEN_MFMA(ROW0)                                                          \
  BARRIER();                                                                     \
  asm volatile("s_waitcnt lgkmcnt(0)" ::: "memory");                             \
  __builtin_amdgcn_s_setprio(1);                                                 \
  _Pragma("unroll") for (int m = 0; m < 4; ++m)                                  \
  _Pragma("unroll") for (int n = 0; n < 4; ++n)                                  \
    acc[(ROW0) + m][n] = __builtin_amdgcn_mfma_f32_16x16x32_bf16(                \
        a[m], b[n], acc[(ROW0) + m][n], 0, 0, 0);                                \
  __builtin_amdgcn_s_setprio(0);

// One K-tile, 4 phases, ONE half-tile staged per phase (m201 cadence).
#define TILE_BODY(T_, DB_, TP_, SBHI_, SBLO_, FULL_)                             \
  { /* ph0: ks0 m0-3 (8 ds_read) | stage A-lo(t+1) */                            \
    _Pragma("unroll") for (int m = 0; m < 4; ++m) a[m] = LDA8(0, DB_, m);        \
    _Pragma("unroll") for (int n = 0; n < 4; ++n) b[n] = LDB8(0, TP_, n);        \
    STAGE_AH((T_) + 1, 0, (DB_) ^ 1)                                             \
    OPEN_MFMA(0)                                                                 \
    BARRIER();                                                                   \
    /* ph1: ks0 m4-7 (4 ds_read, reuse b) | stage A-hi(t+1) */                   \
    _Pragma("unroll") for (int m = 0; m < 4; ++m) a[m] = LDA8(0, DB_, 4 + m);    \
    STAGE_AH((T_) + 1, 1, (DB_) ^ 1)                                             \
    OPEN_MFMA(4)                                                                 \
    BARRIER();                                                                   \
    /* ph2: ks1 m0-3 (8 ds_read) | stage B-hi(t+1) */                            \
    _Pragma("unroll") for (int m = 0; m < 4; ++m) a[m] = LDA8(1, DB_, m);        \
    _Pragma("unroll") for (int n = 0; n < 4; ++n) b[n] = LDB8(1, TP_, n);        \
    STAGE_BH((T_) + 1, 1, SBHI_)                                                 \
    OPEN_MFMA(0)                                                                 \
    BARRIER();                                                                   \
    /* ph3: ks1 m4-7 (4 ds_read) | stage B-lo(t+2) | counted wait */             \
    _Pragma("unroll") for (int m = 0; m < 4; ++m) a[m] = LDA8(1, DB_, 4 + m);    \
    STAGE_BH((T_) + 2, 0, SBLO_)                                                 \
    OPEN_MFMA(4)                                                                 \
    if (FULL_) { asm volatile("s_waitcnt vmcnt(2)" ::: "memory"); }              \
    else       { asm volatile("s_waitcnt vmcnt(0)" ::: "memory"); }              \
    BARRIER();                                                                   \
  }

  // prologue: A(0)->dbuf0, Blo(0)->slot0, Bhi(0)->slot1, Blo(1)->slot2;
  // vmcnt(2) publishes tile 0 (8 oldest), leaves Blo(1) in flight.
  STAGE_AH(0, 0, 0)
  STAGE_AH(0, 1, 0)
  STAGE_BH(0, 0, 0)
  STAGE_BH(0, 1, 1)
  STAGE_BH(1, 0, 2)
  asm volatile("s_waitcnt vmcnt(2)" ::: "memory");
  BARRIER();

  for (int kt = 0; kt < NT; kt += 2) {
    // tile kt (even): dbuf 0, B slots {0,1}; Bhi(kt+1)->3, Blo(kt+2)->0
    TILE_BODY(kt, 0, 0, 3, 0, (kt + 2 < NT))
    // tile kt+1 (odd): dbuf 1, B slots {2,3}; Bhi(kt+2)->1, Blo(kt+3)->2
    TILE_BODY(kt + 1, 1, 1, 1, 2, (kt + 3 < NT))
  }

  // epilogue — C/D layout: col = lane&15, row = (lane>>4)*4 + j  [m89/m91]
  const int orow = tm * BM + wr * 128;
  const int ocol = tn * BN + wc * 64;
  const int rsub = g * 4;
#pragma unroll
  for (int n = 0; n < 4; ++n) {
    const int gn = ocol + n * 16 + lr;
    const float bv = bias[gn];
    const float sv = scale[gn];
#pragma unroll
    for (int m = 0; m < 8; ++m) {
#pragma unroll
      for (int j = 0; j < 4; ++j) {
        const int gm = orow + m * 16 + rsub + j;
        float v = (acc[m][n][j] + bv) * sv;
        if (EPI == 0) {
          const float gl = 0.5f * v * (1.0f + erff(v * 0.70710678118654752440f));
          ((unsigned short*)Cout)[(size_t)gm * N + gn] = f2bf(gl);
        } else {
          ((float*)Cout)[(size_t)gm * N + gn] = v;
        }
      }
    }
  }
#undef STAGE_AH
#undef STAGE_BH
#undef LDA8
#undef LDB8
#undef OPEN_MFMA
#undef TILE_BODY
#undef BARRIER
}

extern "C" void kernel_launch(void* const* d_in, const int* in_sizes, int n_in,
                              void* d_out, int out_size, void* d_ws, size_t ws_size,
                              hipStream_t stream) {
  const int T = 16384, H = 2048, H2 = 4096;
  const float* x  = (const float*)d_in[0];
  const float* w1 = (const float*)d_in[1];
  const float* b1 = (const float*)d_in[2];
  const float* s1 = (const float*)d_in[3];
  const float* w2 = (const float*)d_in[4];
  const float* b2 = (const float*)d_in[5];
  const float* s2 = (const float*)d_in[6];

  // workspace (bf16): xb 64MiB | w1b 16MiB | w2b 16MiB | h 128MiB  (224 MiB)
  unsigned short* xb  = (unsigned short*)d_ws;
  unsigned short* w1b = xb  + (size_t)T  * H;
  unsigned short* w2b = w1b + (size_t)H2 * H;
  unsigned short* hb  = w2b + (size_t)H  * H2;

  int n4 = T * H / 4;
  cvt_f32_to_bf16<<<(n4 + 255) / 256, 256, 0, stream>>>(x, xb, n4);
  n4 = H2 * H / 4;
  cvt_f32_to_bf16<<<(n4 + 255) / 256, 256, 0, stream>>>(w1, w1b, n4);
  cvt_f32_to_bf16<<<(n4 + 255) / 256, 256, 0, stream>>>(w2, w2b, n4);

  // fc1 + bias + scale + exact GELU -> h (bf16): M=T, N=2H, K=H, grid 1024
  gemm256_v6<0><<<(T / 256) * (H2 / 256), 512, 0, stream>>>(
      xb, w1b, b1, s1, (void*)hb, T, H2, H);
  // fc2 + bias + scale -> y (fp32): M=T, N=H, K=2H, grid 512
  gemm256_v6<1><<<(T / 256) * (H / 256), 512, 0, stream>>>(
      hb, w2b, b2, s2, d_out, T, H, H2);
}